// Round 8
// baseline (294.632 us; speedup 1.0000x reference)
//
#include <hip/hip_runtime.h>
#include <cstdint>
#include <cstddef>

typedef unsigned short ushort_t;
typedef __attribute__((ext_vector_type(8))) short short8;
typedef __attribute__((ext_vector_type(4))) float f32x4;
typedef __attribute__((ext_vector_type(4))) _Float16 half4;
typedef __attribute__((ext_vector_type(8))) _Float16 half8;
typedef __attribute__((ext_vector_type(2))) _Float16 half2;
typedef __attribute__((ext_vector_type(2))) __fp16 fp16v2;
struct half4x2 { half4 lo, hi; };
struct half2x2 { half2 lo, hi; };

__device__ __forceinline__ unsigned short f2bf(float f) {
    unsigned u = __float_as_uint(f);
    u += 0x7fffu + ((u >> 16) & 1u);
    return (unsigned short)(u >> 16);
}
__device__ __forceinline__ float bf2f(unsigned short h) {
    return __uint_as_float((unsigned)h << 16);
}
__device__ __forceinline__ ushort_t f2h(float f) {
    _Float16 h = (_Float16)f;
    return __builtin_bit_cast(unsigned short, h);
}
__device__ __forceinline__ f32x4 zero4() {
    f32x4 z; z[0]=0.f; z[1]=0.f; z[2]=0.f; z[3]=0.f; return z;
}
__device__ __forceinline__ half4 pk4(float a, float b, float cc, float d) {
    half2x2 t;
    t.lo = __builtin_bit_cast(half2, (fp16v2)__builtin_amdgcn_cvt_pkrtz(a, b));
    t.hi = __builtin_bit_cast(half2, (fp16v2)__builtin_amdgcn_cvt_pkrtz(cc, d));
    return __builtin_bit_cast(half4, t);
}
__device__ __forceinline__ void gld_lds16(const ushort_t* g, ushort_t* l) {
    __builtin_amdgcn_global_load_lds(
        (const __attribute__((address_space(1))) void*)g,
        (__attribute__((address_space(3))) void*)l, 16, 0, 0);
}

// ---------------- fused fp32->bf16 convert (x + 4 weights) + rope table, one launch ----------------
__global__ void cvt_all(const float* __restrict__ x,
                        const float* __restrict__ wq, const float* __restrict__ wk,
                        const float* __restrict__ wv, const float* __restrict__ wo,
                        ushort_t* __restrict__ xb,
                        ushort_t* __restrict__ wqb, ushort_t* __restrict__ wkb,
                        ushort_t* __restrict__ wvb, ushort_t* __restrict__ wob,
                        float2* __restrict__ tab) {
    int idx = blockIdx.x * 256 + threadIdx.x;   // grid 12544 blocks exactly
    if (idx >= 3145728) {                        // rope table: 65536 entries
        int i = idx - 3145728;
        int t = i >> 5, p = i & 31;
        float freq = __expf((float)p * -0.2878231366242557f);  // 10000^(-p/32)
        float sn, cs;
        sincosf((float)t * freq, &sn, &cs);
        tab[i] = make_float2(cs, sn);
        return;
    }
    const float* src; ushort_t* dst; int off;
    if (idx < 2097152) { src = x; dst = xb; off = idx; }
    else {
        int r = idx - 2097152;
        int w = r >> 18;
        off = r & 262143;
        src = (w == 0) ? wq : (w == 1) ? wk : (w == 2) ? wv : wo;
        dst = (w == 0) ? wqb : (w == 1) ? wkb : (w == 2) ? wvb : wob;
    }
    float4 v = ((const float4*)src)[off];
    ushort_t o[4];
    o[0] = f2bf(v.x); o[1] = f2bf(v.y); o[2] = f2bf(v.z); o[3] = f2bf(v.w);
    *(ushort4*)(dst + 4*(size_t)off) = *(const ushort4*)o;
}

// ---------------- GEMM core A-ring32: BM=BN=128, BK=32, 4 waves, 3-deep LDS
// ring (48 KiB -> 3 blocks/CU), counted vmcnt(4) across raw s_barrier (the
// session-verified pipe256 idiom, transplanted): prefetch distance 2 means the
// barrier never drains the newest loads -- t+1's loads retire after aging two
// full compute phases, t+2's stay in flight. XOR swizzle as R7 (refcheck'd).
// C = A(Mx1024) W(Nx1024)^T.
__device__ __forceinline__ void gemm_core_ring32(const ushort_t* __restrict__ A,
                                                 const ushort_t* __restrict__ W,
                                                 ushort_t* As, ushort_t* Bs,  // each 3*4096 ushorts
                                                 int m0, int n0, f32x4 (&acc)[4][4]) {
    const int tid  = threadIdx.x;
    const int wave = tid >> 6, lane = tid & 63;
    const int wm = (wave >> 1) * 64, wn = (wave & 1) * 64;
    const int q = lane >> 4, c = lane & 15;
    const int srow = lane >> 2;                      // 0..15: row within 16-row group
    const int gch  = (lane & 3) ^ ((lane >> 3) & 3); // source chunk (involution w/ read side)

    // staging: wave w covers rows {p*64 + w*16 + srow} for p=0,1 (A and B)
    const ushort_t* ag0 = A + (size_t)(m0 +      wave*16 + srow) * 1024 + gch*8;
    const ushort_t* ag1 = A + (size_t)(m0 + 64 + wave*16 + srow) * 1024 + gch*8;
    const ushort_t* bg0 = W + (size_t)(n0 +      wave*16 + srow) * 1024 + gch*8;
    const ushort_t* bg1 = W + (size_t)(n0 + 64 + wave*16 + srow) * 1024 + gch*8;
    // LDS dest wave-uniform base; HW adds lane*16B: row wave*16+(lane>>2), chunk lane&3
    ushort_t* a0 = As + wave*512;
    ushort_t* a1 = As + 2048 + wave*512;
    ushort_t* b0 = Bs + wave*512;
    ushort_t* b1 = Bs + 2048 + wave*512;

    // prologue: stage step0 -> buf0 (4 loads), step1 -> buf1 (4 loads)
    gld_lds16(ag0,      a0);        gld_lds16(ag1,      a1);
    gld_lds16(bg0,      b0);        gld_lds16(bg1,      b1);
    gld_lds16(ag0 + 32, a0 + 4096); gld_lds16(ag1 + 32, a1 + 4096);
    gld_lds16(bg0 + 32, b0 + 4096); gld_lds16(bg1 + 32, b1 + 4096);
    asm volatile("s_waitcnt vmcnt(4)" ::: "memory");   // step0 landed; step1 in flight
    __builtin_amdgcn_s_barrier();

    const int ch = (q ^ ((c >> 1) & 3)) * 8;   // read-side swizzled chunk
    int cur = 0;
    for (int t = 0; t < 32; ++t) {
        const int nx2 = (cur >= 1) ? cur - 1 : 2;      // (t+2)%3
        const bool pf = (t < 30);
        // ---- issue step t+2's stage (other ring slot): 2 steps of aging
        if (pf) {
            const int kc = (t + 2) * 32;
            gld_lds16(ag0 + kc, a0 + nx2*4096);
            gld_lds16(ag1 + kc, a1 + nx2*4096);
            gld_lds16(bg0 + kc, b0 + nx2*4096);
            gld_lds16(bg1 + kc, b1 + nx2*4096);
        }
        // ---- compute current buffer: 8 ds_read_b128, 16 MFMAs
        const ushort_t* Ab = As + cur*4096;
        const ushort_t* Bb = Bs + cur*4096;
        short8 af[4], bf[4];
#pragma unroll
        for (int i = 0; i < 4; ++i)
            af[i] = *(const short8*)(Ab + (wm + i*16 + c)*32 + ch);
#pragma unroll
        for (int j = 0; j < 4; ++j)
            bf[j] = *(const short8*)(Bb + (wn + j*16 + c)*32 + ch);
#pragma unroll
        for (int i = 0; i < 4; ++i)
#pragma unroll
            for (int j = 0; j < 4; ++j)
                acc[i][j] = __builtin_amdgcn_mfma_f32_16x16x32_bf16(af[i], bf[j], acc[i][j], 0, 0, 0);
        // counted wait: retire step t+1's 4 loads (aged 2 phases), keep t+2's
        // 4 in flight across the barrier. Epilogue (t>=30): drain.
        if (pf) { asm volatile("s_waitcnt vmcnt(4)" ::: "memory"); }
        else    { asm volatile("s_waitcnt vmcnt(0)" ::: "memory"); }
        __builtin_amdgcn_s_barrier();
        cur = (cur == 2) ? 0 : cur + 1;
    }
}

// ---------------- GEMM core B (pipelined; used by the 1-round gemm_out):
// BM=256 BN=128 BK=64, 8 waves, 3-deep LDS ring, counted vmcnt(6).
__device__ __forceinline__ void gemm_pipe256(const ushort_t* __restrict__ A,
                                             const ushort_t* __restrict__ W,
                                             ushort_t* __restrict__ As,   // 3*16384
                                             ushort_t* __restrict__ Bs,   // 3*8192
                                             int m0, int n0, f32x4 (&acc)[4][4]) {
    const int tid  = threadIdx.x;
    const int wave = tid >> 6, lane = tid & 63;
    const int wm = (wave >> 1) * 64, wn = (wave & 1) * 64;
    const int q = lane >> 4, c = lane & 15;
    const int srow = lane >> 3;            // 0..7
    const int gch  = (lane & 7) ^ srow;    // swizzled source chunk

    const ushort_t* ag = A + (size_t)(m0 + wave * 8 + srow) * 1024 + gch * 8;
    const ushort_t* bg = W + (size_t)(n0 + wave * 8 + srow) * 1024 + gch * 8;
    ushort_t* adst = As + wave * 512;
    ushort_t* bdst = Bs + wave * 512;

    // prologue: stage tile0 -> buf0, tile1 -> buf1 (6 loads each, per thread)
#pragma unroll
    for (int n = 0; n < 4; ++n) gld_lds16(ag + (size_t)n * 65536,      adst + n * 4096);
#pragma unroll
    for (int n = 0; n < 2; ++n) gld_lds16(bg + (size_t)n * 65536,      bdst + n * 4096);
#pragma unroll
    for (int n = 0; n < 4; ++n) gld_lds16(ag + (size_t)n * 65536 + 64, adst + 16384 + n * 4096);
#pragma unroll
    for (int n = 0; n < 2; ++n) gld_lds16(bg + (size_t)n * 65536 + 64, bdst + 8192 + n * 4096);
    asm volatile("s_waitcnt vmcnt(6)" ::: "memory");   // tile0 landed; tile1 in flight
    __builtin_amdgcn_s_barrier();

    const int ch0 = (q ^ (c & 7)) * 8;
    const int ch1 = ((4 + q) ^ (c & 7)) * 8;
    int cur = 0;
    for (int t = 0; t < 16; ++t) {
        const int nx2 = (cur >= 1) ? cur - 1 : 2;          // (t+2)%3
        const ushort_t* ab = As + cur * 16384 + (wm + c) * 64;
        const ushort_t* bb = Bs + cur * 8192  + (wn + c) * 64;
        const int kc = (t + 2) * 64;
        const bool pf = (t < 14);
        short8 af[4], bf[4];

        // ---- phase 0: sk=0 frags, stage A0,A1,B0 of tile t+2
#pragma unroll
        for (int i = 0; i < 4; ++i) af[i] = *(const short8*)(ab + i * 1024 + ch0);
#pragma unroll
        for (int j = 0; j < 4; ++j) bf[j] = *(const short8*)(bb + j * 1024 + ch0);
        if (pf) {
            gld_lds16(ag + kc,           adst + nx2 * 16384);
            gld_lds16(ag + 65536 + kc,   adst + nx2 * 16384 + 4096);
            gld_lds16(bg + kc,           bdst + nx2 * 8192);
        }
        __builtin_amdgcn_s_barrier();
        asm volatile("s_waitcnt lgkmcnt(0)" ::: "memory");
        __builtin_amdgcn_s_setprio(1);
#pragma unroll
        for (int i = 0; i < 4; ++i)
#pragma unroll
            for (int j = 0; j < 4; ++j)
                acc[i][j] = __builtin_amdgcn_mfma_f32_16x16x32_bf16(af[i], bf[j], acc[i][j], 0, 0, 0);
        __builtin_amdgcn_s_setprio(0);
        __builtin_amdgcn_s_barrier();

        // ---- phase 1: sk=1 frags, stage A2,A3,B1 of tile t+2
#pragma unroll
        for (int i = 0; i < 4; ++i) af[i] = *(const short8*)(ab + i * 1024 + ch1);
#pragma unroll
        for (int j = 0; j < 4; ++j) bf[j] = *(const short8*)(bb + j * 1024 + ch1);
        if (pf) {
            gld_lds16(ag + 131072 + kc,  adst + nx2 * 16384 + 8192);
            gld_lds16(ag + 196608 + kc,  adst + nx2 * 16384 + 12288);
            gld_lds16(bg + 65536 + kc,   bdst + nx2 * 8192 + 4096);
        }
        __builtin_amdgcn_s_barrier();
        asm volatile("s_waitcnt lgkmcnt(0)" ::: "memory");
        __builtin_amdgcn_s_setprio(1);
#pragma unroll
        for (int i = 0; i < 4; ++i)
#pragma unroll
            for (int j = 0; j < 4; ++j)
                acc[i][j] = __builtin_amdgcn_mfma_f32_16x16x32_bf16(af[i], bf[j], acc[i][j], 0, 0, 0);
        __builtin_amdgcn_s_setprio(0);
        // counted wait: retire tile t+1's 6 loads, leave tile t+2's 6 in flight
        if (pf) { asm volatile("s_waitcnt vmcnt(6)" ::: "memory"); }
        else    { asm volatile("s_waitcnt vmcnt(0)" ::: "memory"); }
        __builtin_amdgcn_s_barrier();
        cur = (cur == 2) ? 0 : cur + 1;
    }
}

// Fused QKV projection as one logical N=3072 GEMM, 1536 blocks (flattened),
// T1 bijective XCD swizzle. RoPE fused via table; K/V written in flash's
// MFMA-fragment-tiled layouts. Core: A-ring32 (3-deep ring, counted vmcnt).
__global__ __launch_bounds__(256) void gemm_qkv_kernel(
    const ushort_t* __restrict__ X, const ushort_t* __restrict__ Wq,
    const ushort_t* __restrict__ Wk, const ushort_t* __restrict__ Wv,
    const float2* __restrict__ tab,
    ushort_t* __restrict__ Q, ushort_t* __restrict__ Kt, ushort_t* __restrict__ Vt) {
    __shared__ ushort_t As[3 * 4096];
    __shared__ ushort_t Bs[3 * 4096];
    const int orig = blockIdx.x;                 // 0..1535, 1536 % 8 == 0
    const int wg = (orig & 7) * 192 + (orig >> 3);
    const int my = wg / 24;
    const int n24 = wg - my * 24;
    const int which = n24 >> 3;
    const ushort_t* W = (which == 0) ? Wq : (which == 1) ? Wk : Wv;
    const int m0 = my * 128;
    const int nloc0 = (n24 & 7) * 128;           // 0..896 within the selected matrix

    f32x4 acc[4][4];
#pragma unroll
    for (int i = 0; i < 4; ++i)
#pragma unroll
        for (int j = 0; j < 4; ++j) acc[i][j] = zero4();

    gemm_core_ring32(X, W, As, Bs, m0, nloc0, acc);

    const int lane = threadIdx.x & 63, wave = threadIdx.x >> 6;
    const int q = lane >> 4, c = lane & 15;
    const int wm = (wave >> 1) * 64, wn = (wave & 1) * 64;
    const float scale = (which == 0) ? 0.18033688011112042f : 1.0f;  // 0.125*log2(e) for Q

#pragma unroll
    for (int i = 0; i < 4; ++i)
#pragma unroll
        for (int j = 0; j < 4; ++j) {
            int nn = nloc0 + wn + j*16 + c;      // col within matrix: h*64+d
            int d = nn & 63, h = nn >> 6;
            int pidx = d >> 1;
            float sgn = (d & 1) ? 1.f : -1.f;
#pragma unroll
            for (int r = 0; r < 4; ++r) {
                int mm = m0 + wm + i*16 + q*4 + r;   // row: b*2048+t
                int b = mm >> 11, t = mm & 2047;
                float val = acc[i][j][r];
                if (which == 0) {      // Q: rope + (B,H,T,64) bf16 row-major
                    float partner = __shfl_xor(val, 1);
                    float2 cs = tab[t * 32 + pidx];
                    val = (val * cs.x + sgn * partner * cs.y) * scale;
                    Q[((size_t)((b << 4) + h) * 2048 + t) * 64 + d] = f2bf(val);
                } else if (which == 1) {  // K: rope + scatter into tiled bf16 layout
                    float partner = __shfl_xor(val, 1);
                    float2 cs = tab[t * 32 + pidx];
                    val = val * cs.x + sgn * partner * cs.y;
                    int kb = t >> 6, jn = (t >> 4) & 3, cc2 = t & 15;
                    int ks2 = d >> 5, qq2 = (d >> 3) & 3, e = d & 7;
                    int lane2 = qq2 * 16 + cc2;
                    Kt[((((size_t)((b << 4) + h) * 32 + kb) * 8 + jn * 2 + ks2) << 9) + lane2 * 8 + e] = f2bf(val);
                } else {               // V: scatter into tiled f16 layout
                    int kb = t >> 6, kl = t & 63;
                    int jn = kl >> 4, qq2 = (kl >> 2) & 3;
                    int e = ((jn & 1) << 2) | (kl & 3);
                    int p = ((d >> 4) << 1) | (jn >> 1);
                    int lane2 = qq2 * 16 + (d & 15);
                    Vt[((((size_t)((b << 4) + h) * 32 + kb) * 8 + p) << 9) + lane2 * 8 + e] = f2h(val);
                }
            }
        }
}

__global__ __launch_bounds__(512) void gemm_out_kernel(
    const ushort_t* __restrict__ A, const ushort_t* __restrict__ Wo,
    float* __restrict__ OUT) {
    __shared__ ushort_t As[3 * 16384];
    __shared__ ushort_t Bs[3 * 8192];
    // 256 blocks (32 m-tiles x 8 n-tiles) = exactly 1/CU, XCD-swizzled
    const int orig = blockIdx.x;
    const int wg = (orig & 7) * 32 + (orig >> 3);
    const int m0 = (wg >> 3) * 256, n0 = (wg & 7) * 128;

    f32x4 acc[4][4];
#pragma unroll
    for (int i = 0; i < 4; ++i)
#pragma unroll
        for (int j = 0; j < 4; ++j) acc[i][j] = zero4();

    gemm_pipe256(A, Wo, As, Bs, m0, n0, acc);

    const int lane = threadIdx.x & 63, wave = threadIdx.x >> 6;
    const int q = lane >> 4, c = lane & 15;
    const int wm = (wave >> 1) * 64, wn = (wave & 1) * 64;
#pragma unroll
    for (int i = 0; i < 4; ++i)
#pragma unroll
        for (int j = 0; j < 4; ++j)
#pragma unroll
            for (int r = 0; r < 4; ++r) {
                int mm = m0 + wm + i*16 + q*4 + r;
                int nn = n0 + wn + j*16 + c;
                OUT[(size_t)mm * 1024 + nn] = acc[i][j][r];
            }
}

// ---------------- Flash attention v8: prefetch double-buffer + PV fused x32 f16.
__global__ __launch_bounds__(256, 3) void flash_kernel(
    const ushort_t* __restrict__ Q, const ushort_t* __restrict__ Kt,
    const ushort_t* __restrict__ Vt, ushort_t* __restrict__ AO) {
    __shared__ ushort_t Ks[2][4096];   // 64x64 bf16 K tiles, fragment-tiled
    __shared__ ushort_t Vs[2][4096];   // 64x64 f16 V tiles, fragment-tiled
    const int bh = blockIdx.x;
    const int c0 = 15 - blockIdx.y;             // LPT: big chunks first
    const int w  = threadIdx.x >> 6, lane = threadIdx.x & 63;
    const int q = lane >> 4, c = lane & 15;
    const int qlo = c0 * 128;
    const int nt  = 2 * c0 + 2;                 // 64-key tiles
    const int wq0 = qlo + w * 32;               // this wave's first query
    const int b = bh >> 4, hh = bh & 15;

    const ushort_t* Qp = Q + (size_t)bh * 131072;
    const ushort_t* kt0 = Kt + (size_t)bh * 131072;
    const ushort_t* vt0 = Vt + (size_t)bh * 131072;

    short8 qf[2][2];
#pragma unroll
    for (int m = 0; m < 2; ++m)
#pragma unroll
        for (int ks = 0; ks < 2; ++ks)
            qf[m][ks] = *(const short8*)(Qp + (size_t)(wq0 + m*16 + c) * 64 + ks * 32 + q * 8);

    f32x4 ot[2][4];
#pragma unroll
    for (int m = 0; m < 2; ++m)
#pragma unroll
        for (int dj = 0; dj < 4; ++dj) ot[m][dj] = zero4();
    float lpart[2] = {0.f, 0.f};

    // prologue: stage tile 0 -> buf 0
#pragma unroll
    for (int s = 0; s < 2; ++s) {
        gld_lds16(kt0 + (s*4 + w)*512 + lane*8, &Ks[0][(s*4 + w)*512]);
        gld_lds16(vt0 + (s*4 + w)*512 + lane*8, &Vs[0][(s*4 + w)*512]);
    }
    asm volatile("s_waitcnt vmcnt(0)" ::: "memory");
    __syncthreads();

    for (int kb = 0; kb < nt; ++kb) {
        const int cur = kb & 1;
        // ---- issue next tile's stage FIRST: latency hides under this tile's compute
        if (kb + 1 < nt) {
            const ushort_t* kt = kt0 + (size_t)(kb + 1) * 4096;
            const ushort_t* vt = vt0 + (size_t)(kb + 1) * 4096;
#pragma unroll
            for (int s = 0; s < 2; ++s) {
                gld_lds16(kt + (s*4 + w)*512 + lane*8, &Ks[cur ^ 1][(s*4 + w)*512]);
                gld_lds16(vt + (s*4 + w)*512 + lane*8, &Vs[cur ^ 1][(s*4 + w)*512]);
            }
        }

        if (kb * 64 <= wq0 + 31) {              // not fully masked for this wave
            const ushort_t* Kb = &Ks[cur][0];
            const ushort_t* Vb = &Vs[cur][0];
            // ---- S^T = K Q^T : row=key(q*4+r), col=query(c)
            f32x4 st[2][4];
#pragma unroll
            for (int jn = 0; jn < 4; ++jn) {
                short8 kf0 = *(const short8*)(Kb + (jn*2+0)*512 + lane*8);
                short8 kf1 = *(const short8*)(Kb + (jn*2+1)*512 + lane*8);
#pragma unroll
                for (int m = 0; m < 2; ++m) {
                    f32x4 t0 = __builtin_amdgcn_mfma_f32_16x16x32_bf16(kf0, qf[m][0], zero4(), 0, 0, 0);
                    st[m][jn] = __builtin_amdgcn_mfma_f32_16x16x32_bf16(kf1, qf[m][1], t0, 0, 0, 0);
                }
            }
            if (kb * 64 + 63 > wq0) {           // partial (diagonal) tile: mask
#pragma unroll
                for (int m = 0; m < 2; ++m) {
                    int query = wq0 + m * 16 + c;
#pragma unroll
                    for (int jn = 0; jn < 4; ++jn)
#pragma unroll
                        for (int r = 0; r < 4; ++r)
                            if (kb * 64 + jn * 16 + q * 4 + r > query) st[m][jn][r] = -1e30f;
                }
            }
            // ---- p = exp2(s'); per-lane l partials; pack f16 B-frags
            half4 pa[2][4];
#pragma unroll
            for (int m = 0; m < 2; ++m)
#pragma unroll
                for (int jn = 0; jn < 4; ++jn) {
                    float p0 = exp2f(st[m][jn][0]), p1 = exp2f(st[m][jn][1]);
                    float p2 = exp2f(st[m][jn][2]), p3 = exp2f(st[m][jn][3]);
                    lpart[m] += (p0 + p1) + (p2 + p3);
                    pa[m][jn] = pk4(p0, p1, p2, p3);
                }
            // ---- O^T += V^T P^T  (fused x32: one MFMA per (jnp,dj,m))
#pragma unroll
            for (int jnp = 0; jnp < 2; ++jnp)
#pragma unroll
                for (int dj = 0; dj < 4; ++dj) {
                    half8 vv8 = __builtin_bit_cast(half8,
                        *(const short8*)(Vb + (dj*2 + jnp)*512 + lane*8));
#pragma unroll
                    for (int m = 0; m < 2; ++m) {
                        half4x2 pb;
                        pb.lo = pa[m][2*jnp];
                        pb.hi = pa[m][2*jnp+1];
                        ot[m][dj] = __builtin_amdgcn_mfma_f32_16x16x32_f16(
                            vv8, __builtin_bit_cast(half8, pb), ot[m][dj], 0, 0, 0);
                    }
                }
        }

        // next tile landed + all waves done reading buf[cur^1] (writes target it next iter)
        asm volatile("s_waitcnt vmcnt(0)" ::: "memory");
        __syncthreads();
    }

    // ---- epilogue: quad-reduce l (keys on lanes c,c+16,c+32,c+48), normalize, store
#pragma unroll
    for (int m = 0; m < 2; ++m) {
        float l = lpart[m];
        l += __shfl_xor(l, 16);
        l += __shfl_xor(l, 32);
        float inv = 1.f / l;
        int t = wq0 + m * 16 + c;
        ushort_t* base = AO + ((size_t)b * 2048 + t) * 1024 + hh * 64;
#pragma unroll
        for (int dj = 0; dj < 4; ++dj) {
            ushort4 o;
            o.x = f2bf(ot[m][dj][0] * inv);
            o.y = f2bf(ot[m][dj][1] * inv);
            o.z = f2bf(ot[m][dj][2] * inv);
            o.w = f2bf(ot[m][dj][3] * inv);
            *(ushort4*)(base + dj * 16 + q * 4) = o;
        }
    }
}

extern "C" void kernel_launch(void* const* d_in, const int* in_sizes, int n_in,
                              void* d_out, int out_size, void* d_ws, size_t ws_size,
                              hipStream_t stream) {
    const float* x  = (const float*)d_in[0];
    const float* Wq = (const float*)d_in[2];
    const float* Wk = (const float*)d_in[3];
    const float* Wv = (const float*)d_in[4];
    const float* Wo = (const float*)d_in[5];
    float* out = (float*)d_out;

    ushort_t* ws  = (ushort_t*)d_ws;
    ushort_t* Xb  = ws;                 // 8192x1024 bf16; reused as AO after projections
    ushort_t* Qb  = ws + 8388608;
    ushort_t* Ktb = ws + 16777216;      // bf16, MFMA-fragment-tiled (bh,kb,p,lane,8)
    ushort_t* Vtb = ws + 25165824;      // f16,  MFMA-fragment-tiled (bh,kb,p,lane,8)
    ushort_t* Wqb = ws + 33554432;
    ushort_t* Wkb = Wqb + 1048576;
    ushort_t* Wvb = Wkb + 1048576;
    ushort_t* Wob = Wvb + 1048576;
    float2*   tab = (float2*)(ws + 37748736);   // 512 KB rope table

    cvt_all<<<12544, 256, 0, stream>>>(x, Wq, Wk, Wv, Wo, Xb, Wqb, Wkb, Wvb, Wob, tab);

    // fused QKV: one logical N=3072 GEMM; 128x128 BK=32 3-deep ring core
    gemm_qkv_kernel<<<1536, 256, 0, stream>>>(Xb, Wqb, Wkb, Wvb, tab, Qb, Ktb, Vtb);

    flash_kernel<<<dim3(64, 16), 256, 0, stream>>>(Qb, Ktb, Vtb, Xb);

    gemm_out_kernel<<<256, 512, 0, stream>>>(Xb, Wob, out);
}

// Round 9
// 293.495 us; speedup vs baseline: 1.0039x; 1.0039x over previous
//
#include <hip/hip_runtime.h>
#include <cstdint>
#include <cstddef>

typedef unsigned short ushort_t;
typedef __attribute__((ext_vector_type(8))) short short8;
typedef __attribute__((ext_vector_type(4))) float f32x4;
typedef __attribute__((ext_vector_type(4))) _Float16 half4;
typedef __attribute__((ext_vector_type(8))) _Float16 half8;
typedef __attribute__((ext_vector_type(2))) _Float16 half2;
typedef __attribute__((ext_vector_type(2))) __fp16 fp16v2;
struct half4x2 { half4 lo, hi; };
struct half2x2 { half2 lo, hi; };

__device__ __forceinline__ unsigned short f2bf(float f) {
    unsigned u = __float_as_uint(f);
    u += 0x7fffu + ((u >> 16) & 1u);
    return (unsigned short)(u >> 16);
}
__device__ __forceinline__ float bf2f(unsigned short h) {
    return __uint_as_float((unsigned)h << 16);
}
__device__ __forceinline__ ushort_t f2h(float f) {
    _Float16 h = (_Float16)f;
    return __builtin_bit_cast(unsigned short, h);
}
__device__ __forceinline__ f32x4 zero4() {
    f32x4 z; z[0]=0.f; z[1]=0.f; z[2]=0.f; z[3]=0.f; return z;
}
__device__ __forceinline__ half4 pk4(float a, float b, float cc, float d) {
    half2x2 t;
    t.lo = __builtin_bit_cast(half2, (fp16v2)__builtin_amdgcn_cvt_pkrtz(a, b));
    t.hi = __builtin_bit_cast(half2, (fp16v2)__builtin_amdgcn_cvt_pkrtz(cc, d));
    return __builtin_bit_cast(half4, t);
}
__device__ __forceinline__ void gld_lds16(const ushort_t* g, ushort_t* l) {
    __builtin_amdgcn_global_load_lds(
        (const __attribute__((address_space(1))) void*)g,
        (__attribute__((address_space(3))) void*)l, 16, 0, 0);
}

// ---------------- fused fp32->bf16 convert (x + 4 weights) + rope table, one launch ----------------
__global__ void cvt_all(const float* __restrict__ x,
                        const float* __restrict__ wq, const float* __restrict__ wk,
                        const float* __restrict__ wv, const float* __restrict__ wo,
                        ushort_t* __restrict__ xb,
                        ushort_t* __restrict__ wqb, ushort_t* __restrict__ wkb,
                        ushort_t* __restrict__ wvb, ushort_t* __restrict__ wob,
                        float2* __restrict__ tab) {
    int idx = blockIdx.x * 256 + threadIdx.x;   // grid 12544 blocks exactly
    if (idx >= 3145728) {                        // rope table: 65536 entries
        int i = idx - 3145728;
        int t = i >> 5, p = i & 31;
        float freq = __expf((float)p * -0.2878231366242557f);  // 10000^(-p/32)
        float sn, cs;
        sincosf((float)t * freq, &sn, &cs);
        tab[i] = make_float2(cs, sn);
        return;
    }
    const float* src; ushort_t* dst; int off;
    if (idx < 2097152) { src = x; dst = xb; off = idx; }
    else {
        int r = idx - 2097152;
        int w = r >> 18;
        off = r & 262143;
        src = (w == 0) ? wq : (w == 1) ? wk : (w == 2) ? wv : wo;
        dst = (w == 0) ? wqb : (w == 1) ? wkb : (w == 2) ? wvb : wob;
    }
    float4 v = ((const float4*)src)[off];
    ushort_t o[4];
    o[0] = f2bf(v.x); o[1] = f2bf(v.y); o[2] = f2bf(v.z); o[3] = f2bf(v.w);
    *(ushort4*)(dst + 4*(size_t)off) = *(const ushort4*)o;
}

// ---------------- GEMM core A-db32u: BM=BN=128, BK=32, 4 waves, 2-phase
// double-buffer (32 KiB LDS -> 4+ blocks/CU, the m114 co-residency lever).
// R7's proven core (104 us) with the K-loop HAND-UNROLLED x2 so buffer bases
// become compile-time immediates (ds_read offset:N / static gld_lds dests) --
// removes the cur-dependent address VALU (R7: VALUBusy 39%). Op order is
// byte-identical to R7. C = A(Mx1024) W(Nx1024)^T.
__device__ __forceinline__ void gemm_core_db32(const ushort_t* __restrict__ A,
                                               const ushort_t* __restrict__ W,
                                               ushort_t* As, ushort_t* Bs,  // each 2*4096 ushorts
                                               int m0, int n0, f32x4 (&acc)[4][4]) {
    const int tid  = threadIdx.x;
    const int wave = tid >> 6, lane = tid & 63;
    const int wm = (wave >> 1) * 64, wn = (wave & 1) * 64;
    const int q = lane >> 4, c = lane & 15;
    const int srow = lane >> 2;                      // 0..15: row within 16-row group
    const int gch  = (lane & 3) ^ ((lane >> 3) & 3); // source chunk (involution w/ read side)

    // staging: wave w covers rows {p*64 + w*16 + srow} for p=0,1 (A and B)
    const ushort_t* ag0 = A + (size_t)(m0 +      wave*16 + srow) * 1024 + gch*8;
    const ushort_t* ag1 = A + (size_t)(m0 + 64 + wave*16 + srow) * 1024 + gch*8;
    const ushort_t* bg0 = W + (size_t)(n0 +      wave*16 + srow) * 1024 + gch*8;
    const ushort_t* bg1 = W + (size_t)(n0 + 64 + wave*16 + srow) * 1024 + gch*8;
    // LDS dest wave-uniform base; HW adds lane*16B: row wave*16+(lane>>2), chunk lane&3
    ushort_t* a0 = As + wave*512;
    ushort_t* a1 = As + 2048 + wave*512;
    ushort_t* b0 = Bs + wave*512;
    ushort_t* b1 = Bs + 2048 + wave*512;

    // prologue: stage K-step 0 into buffer 0
    gld_lds16(ag0, a0); gld_lds16(ag1, a1);
    gld_lds16(bg0, b0); gld_lds16(bg1, b1);
    __syncthreads();                       // drain + publish

    const int ch = (q ^ ((c >> 1) & 3)) * 8;   // read-side swizzled chunk
    const ushort_t* aR = As + (wm + c)*32 + ch;
    const ushort_t* bR = Bs + (wn + c)*32 + ch;

    for (int t = 0; t < 32; t += 2) {
        // ---- step t: stage step t+1 -> buf1 (always: t<=30 so t+1<32), compute buf0
        {
            const int kc = (t + 1) * 32;
            gld_lds16(ag0 + kc, a0 + 4096);
            gld_lds16(ag1 + kc, a1 + 4096);
            gld_lds16(bg0 + kc, b0 + 4096);
            gld_lds16(bg1 + kc, b1 + 4096);
        }
        {
            short8 af[4], bf[4];
#pragma unroll
            for (int i = 0; i < 4; ++i) af[i] = *(const short8*)(aR + i*512);
#pragma unroll
            for (int j = 0; j < 4; ++j) bf[j] = *(const short8*)(bR + j*512);
#pragma unroll
            for (int i = 0; i < 4; ++i)
#pragma unroll
                for (int j = 0; j < 4; ++j)
                    acc[i][j] = __builtin_amdgcn_mfma_f32_16x16x32_bf16(af[i], bf[j], acc[i][j], 0, 0, 0);
        }
        __syncthreads();

        // ---- step t+1: stage step t+2 -> buf0 (skip at t=30), compute buf1
        if (t < 30) {
            const int kc = (t + 2) * 32;
            gld_lds16(ag0 + kc, a0);
            gld_lds16(ag1 + kc, a1);
            gld_lds16(bg0 + kc, b0);
            gld_lds16(bg1 + kc, b1);
        }
        {
            short8 af[4], bf[4];
#pragma unroll
            for (int i = 0; i < 4; ++i) af[i] = *(const short8*)(aR + 4096 + i*512);
#pragma unroll
            for (int j = 0; j < 4; ++j) bf[j] = *(const short8*)(bR + 4096 + j*512);
#pragma unroll
            for (int i = 0; i < 4; ++i)
#pragma unroll
                for (int j = 0; j < 4; ++j)
                    acc[i][j] = __builtin_amdgcn_mfma_f32_16x16x32_bf16(af[i], bf[j], acc[i][j], 0, 0, 0);
        }
        __syncthreads();
    }
}

// ---------------- GEMM core B (pipelined; used by the 1-round gemm_out):
// BM=256 BN=128 BK=64, 8 waves, 3-deep LDS ring, counted vmcnt(6).
__device__ __forceinline__ void gemm_pipe256(const ushort_t* __restrict__ A,
                                             const ushort_t* __restrict__ W,
                                             ushort_t* __restrict__ As,   // 3*16384
                                             ushort_t* __restrict__ Bs,   // 3*8192
                                             int m0, int n0, f32x4 (&acc)[4][4]) {
    const int tid  = threadIdx.x;
    const int wave = tid >> 6, lane = tid & 63;
    const int wm = (wave >> 1) * 64, wn = (wave & 1) * 64;
    const int q = lane >> 4, c = lane & 15;
    const int srow = lane >> 3;            // 0..7
    const int gch  = (lane & 7) ^ srow;    // swizzled source chunk

    const ushort_t* ag = A + (size_t)(m0 + wave * 8 + srow) * 1024 + gch * 8;
    const ushort_t* bg = W + (size_t)(n0 + wave * 8 + srow) * 1024 + gch * 8;
    ushort_t* adst = As + wave * 512;
    ushort_t* bdst = Bs + wave * 512;

    // prologue: stage tile0 -> buf0, tile1 -> buf1 (6 loads each, per thread)
#pragma unroll
    for (int n = 0; n < 4; ++n) gld_lds16(ag + (size_t)n * 65536,      adst + n * 4096);
#pragma unroll
    for (int n = 0; n < 2; ++n) gld_lds16(bg + (size_t)n * 65536,      bdst + n * 4096);
#pragma unroll
    for (int n = 0; n < 4; ++n) gld_lds16(ag + (size_t)n * 65536 + 64, adst + 16384 + n * 4096);
#pragma unroll
    for (int n = 0; n < 2; ++n) gld_lds16(bg + (size_t)n * 65536 + 64, bdst + 8192 + n * 4096);
    asm volatile("s_waitcnt vmcnt(6)" ::: "memory");   // tile0 landed; tile1 in flight
    __builtin_amdgcn_s_barrier();

    const int ch0 = (q ^ (c & 7)) * 8;
    const int ch1 = ((4 + q) ^ (c & 7)) * 8;
    int cur = 0;
    for (int t = 0; t < 16; ++t) {
        const int nx2 = (cur >= 1) ? cur - 1 : 2;          // (t+2)%3
        const ushort_t* ab = As + cur * 16384 + (wm + c) * 64;
        const ushort_t* bb = Bs + cur * 8192  + (wn + c) * 64;
        const int kc = (t + 2) * 64;
        const bool pf = (t < 14);
        short8 af[4], bf[4];

        // ---- phase 0: sk=0 frags, stage A0,A1,B0 of tile t+2
#pragma unroll
        for (int i = 0; i < 4; ++i) af[i] = *(const short8*)(ab + i * 1024 + ch0);
#pragma unroll
        for (int j = 0; j < 4; ++j) bf[j] = *(const short8*)(bb + j * 1024 + ch0);
        if (pf) {
            gld_lds16(ag + kc,           adst + nx2 * 16384);
            gld_lds16(ag + 65536 + kc,   adst + nx2 * 16384 + 4096);
            gld_lds16(bg + kc,           bdst + nx2 * 8192);
        }
        __builtin_amdgcn_s_barrier();
        asm volatile("s_waitcnt lgkmcnt(0)" ::: "memory");
        __builtin_amdgcn_s_setprio(1);
#pragma unroll
        for (int i = 0; i < 4; ++i)
#pragma unroll
            for (int j = 0; j < 4; ++j)
                acc[i][j] = __builtin_amdgcn_mfma_f32_16x16x32_bf16(af[i], bf[j], acc[i][j], 0, 0, 0);
        __builtin_amdgcn_s_setprio(0);
        __builtin_amdgcn_s_barrier();

        // ---- phase 1: sk=1 frags, stage A2,A3,B1 of tile t+2
#pragma unroll
        for (int i = 0; i < 4; ++i) af[i] = *(const short8*)(ab + i * 1024 + ch1);
#pragma unroll
        for (int j = 0; j < 4; ++j) bf[j] = *(const short8*)(bb + j * 1024 + ch1);
        if (pf) {
            gld_lds16(ag + 131072 + kc,  adst + nx2 * 16384 + 8192);
            gld_lds16(ag + 196608 + kc,  adst + nx2 * 16384 + 12288);
            gld_lds16(bg + 65536 + kc,   bdst + nx2 * 8192 + 4096);
        }
        __builtin_amdgcn_s_barrier();
        asm volatile("s_waitcnt lgkmcnt(0)" ::: "memory");
        __builtin_amdgcn_s_setprio(1);
#pragma unroll
        for (int i = 0; i < 4; ++i)
#pragma unroll
            for (int j = 0; j < 4; ++j)
                acc[i][j] = __builtin_amdgcn_mfma_f32_16x16x32_bf16(af[i], bf[j], acc[i][j], 0, 0, 0);
        __builtin_amdgcn_s_setprio(0);
        // counted wait: retire tile t+1's 6 loads, leave tile t+2's 6 in flight
        if (pf) { asm volatile("s_waitcnt vmcnt(6)" ::: "memory"); }
        else    { asm volatile("s_waitcnt vmcnt(0)" ::: "memory"); }
        __builtin_amdgcn_s_barrier();
        cur = (cur == 2) ? 0 : cur + 1;
    }
}

// Fused QKV projection as one logical N=3072 GEMM, 1536 blocks (flattened),
// T1 bijective XCD swizzle. RoPE fused via table; K/V written in flash's
// MFMA-fragment-tiled layouts. Core: A-db32u (R7's 104us core, unrolled x2).
__global__ __launch_bounds__(256) void gemm_qkv_kernel(
    const ushort_t* __restrict__ X, const ushort_t* __restrict__ Wq,
    const ushort_t* __restrict__ Wk, const ushort_t* __restrict__ Wv,
    const float2* __restrict__ tab,
    ushort_t* __restrict__ Q, ushort_t* __restrict__ Kt, ushort_t* __restrict__ Vt) {
    __shared__ ushort_t As[2 * 4096];
    __shared__ ushort_t Bs[2 * 4096];
    const int orig = blockIdx.x;                 // 0..1535, 1536 % 8 == 0
    const int wg = (orig & 7) * 192 + (orig >> 3);
    const int my = wg / 24;
    const int n24 = wg - my * 24;
    const int which = n24 >> 3;
    const ushort_t* W = (which == 0) ? Wq : (which == 1) ? Wk : Wv;
    const int m0 = my * 128;
    const int nloc0 = (n24 & 7) * 128;           // 0..896 within the selected matrix

    f32x4 acc[4][4];
#pragma unroll
    for (int i = 0; i < 4; ++i)
#pragma unroll
        for (int j = 0; j < 4; ++j) acc[i][j] = zero4();

    gemm_core_db32(X, W, As, Bs, m0, nloc0, acc);

    const int lane = threadIdx.x & 63, wave = threadIdx.x >> 6;
    const int q = lane >> 4, c = lane & 15;
    const int wm = (wave >> 1) * 64, wn = (wave & 1) * 64;
    const float scale = (which == 0) ? 0.18033688011112042f : 1.0f;  // 0.125*log2(e) for Q

#pragma unroll
    for (int i = 0; i < 4; ++i)
#pragma unroll
        for (int j = 0; j < 4; ++j) {
            int nn = nloc0 + wn + j*16 + c;      // col within matrix: h*64+d
            int d = nn & 63, h = nn >> 6;
            int pidx = d >> 1;
            float sgn = (d & 1) ? 1.f : -1.f;
#pragma unroll
            for (int r = 0; r < 4; ++r) {
                int mm = m0 + wm + i*16 + q*4 + r;   // row: b*2048+t
                int b = mm >> 11, t = mm & 2047;
                float val = acc[i][j][r];
                if (which == 0) {      // Q: rope + (B,H,T,64) bf16 row-major
                    float partner = __shfl_xor(val, 1);
                    float2 cs = tab[t * 32 + pidx];
                    val = (val * cs.x + sgn * partner * cs.y) * scale;
                    Q[((size_t)((b << 4) + h) * 2048 + t) * 64 + d] = f2bf(val);
                } else if (which == 1) {  // K: rope + scatter into tiled bf16 layout
                    float partner = __shfl_xor(val, 1);
                    float2 cs = tab[t * 32 + pidx];
                    val = val * cs.x + sgn * partner * cs.y;
                    int kb = t >> 6, jn = (t >> 4) & 3, cc2 = t & 15;
                    int ks2 = d >> 5, qq2 = (d >> 3) & 3, e = d & 7;
                    int lane2 = qq2 * 16 + cc2;
                    Kt[((((size_t)((b << 4) + h) * 32 + kb) * 8 + jn * 2 + ks2) << 9) + lane2 * 8 + e] = f2bf(val);
                } else {               // V: scatter into tiled f16 layout
                    int kb = t >> 6, kl = t & 63;
                    int jn = kl >> 4, qq2 = (kl >> 2) & 3;
                    int e = ((jn & 1) << 2) | (kl & 3);
                    int p = ((d >> 4) << 1) | (jn >> 1);
                    int lane2 = qq2 * 16 + (d & 15);
                    Vt[((((size_t)((b << 4) + h) * 32 + kb) * 8 + p) << 9) + lane2 * 8 + e] = f2h(val);
                }
            }
        }
}

__global__ __launch_bounds__(512) void gemm_out_kernel(
    const ushort_t* __restrict__ A, const ushort_t* __restrict__ Wo,
    float* __restrict__ OUT) {
    __shared__ ushort_t As[3 * 16384];
    __shared__ ushort_t Bs[3 * 8192];
    // 256 blocks (32 m-tiles x 8 n-tiles) = exactly 1/CU, XCD-swizzled
    const int orig = blockIdx.x;
    const int wg = (orig & 7) * 32 + (orig >> 3);
    const int m0 = (wg >> 3) * 256, n0 = (wg & 7) * 128;

    f32x4 acc[4][4];
#pragma unroll
    for (int i = 0; i < 4; ++i)
#pragma unroll
        for (int j = 0; j < 4; ++j) acc[i][j] = zero4();

    gemm_pipe256(A, Wo, As, Bs, m0, n0, acc);

    const int lane = threadIdx.x & 63, wave = threadIdx.x >> 6;
    const int q = lane >> 4, c = lane & 15;
    const int wm = (wave >> 1) * 64, wn = (wave & 1) * 64;
#pragma unroll
    for (int i = 0; i < 4; ++i)
#pragma unroll
        for (int j = 0; j < 4; ++j)
#pragma unroll
            for (int r = 0; r < 4; ++r) {
                int mm = m0 + wm + i*16 + q*4 + r;
                int nn = n0 + wn + j*16 + c;
                OUT[(size_t)mm * 1024 + nn] = acc[i][j][r];
            }
}

// ---------------- Flash attention v9: v8 + T5 setprio around QK and PV MFMA
// clusters (m191: +4-7% attn, independent blocks at multi-block/CU occupancy).
__global__ __launch_bounds__(256, 3) void flash_kernel(
    const ushort_t* __restrict__ Q, const ushort_t* __restrict__ Kt,
    const ushort_t* __restrict__ Vt, ushort_t* __restrict__ AO) {
    __shared__ ushort_t Ks[2][4096];   // 64x64 bf16 K tiles, fragment-tiled
    __shared__ ushort_t Vs[2][4096];   // 64x64 f16 V tiles, fragment-tiled
    const int bh = blockIdx.x;
    const int c0 = 15 - blockIdx.y;             // LPT: big chunks first
    const int w  = threadIdx.x >> 6, lane = threadIdx.x & 63;
    const int q = lane >> 4, c = lane & 15;
    const int qlo = c0 * 128;
    const int nt  = 2 * c0 + 2;                 // 64-key tiles
    const int wq0 = qlo + w * 32;               // this wave's first query
    const int b = bh >> 4, hh = bh & 15;

    const ushort_t* Qp = Q + (size_t)bh * 131072;
    const ushort_t* kt0 = Kt + (size_t)bh * 131072;
    const ushort_t* vt0 = Vt + (size_t)bh * 131072;

    short8 qf[2][2];
#pragma unroll
    for (int m = 0; m < 2; ++m)
#pragma unroll
        for (int ks = 0; ks < 2; ++ks)
            qf[m][ks] = *(const short8*)(Qp + (size_t)(wq0 + m*16 + c) * 64 + ks * 32 + q * 8);

    f32x4 ot[2][4];
#pragma unroll
    for (int m = 0; m < 2; ++m)
#pragma unroll
        for (int dj = 0; dj < 4; ++dj) ot[m][dj] = zero4();
    float lpart[2] = {0.f, 0.f};

    // prologue: stage tile 0 -> buf 0
#pragma unroll
    for (int s = 0; s < 2; ++s) {
        gld_lds16(kt0 + (s*4 + w)*512 + lane*8, &Ks[0][(s*4 + w)*512]);
        gld_lds16(vt0 + (s*4 + w)*512 + lane*8, &Vs[0][(s*4 + w)*512]);
    }
    asm volatile("s_waitcnt vmcnt(0)" ::: "memory");
    __syncthreads();

    for (int kb = 0; kb < nt; ++kb) {
        const int cur = kb & 1;
        // ---- issue next tile's stage FIRST: latency hides under this tile's compute
        if (kb + 1 < nt) {
            const ushort_t* kt = kt0 + (size_t)(kb + 1) * 4096;
            const ushort_t* vt = vt0 + (size_t)(kb + 1) * 4096;
#pragma unroll
            for (int s = 0; s < 2; ++s) {
                gld_lds16(kt + (s*4 + w)*512 + lane*8, &Ks[cur ^ 1][(s*4 + w)*512]);
                gld_lds16(vt + (s*4 + w)*512 + lane*8, &Vs[cur ^ 1][(s*4 + w)*512]);
            }
        }

        if (kb * 64 <= wq0 + 31) {              // not fully masked for this wave
            const ushort_t* Kb = &Ks[cur][0];
            const ushort_t* Vb = &Vs[cur][0];
            // ---- S^T = K Q^T : row=key(q*4+r), col=query(c)
            f32x4 st[2][4];
            __builtin_amdgcn_s_setprio(1);
#pragma unroll
            for (int jn = 0; jn < 4; ++jn) {
                short8 kf0 = *(const short8*)(Kb + (jn*2+0)*512 + lane*8);
                short8 kf1 = *(const short8*)(Kb + (jn*2+1)*512 + lane*8);
#pragma unroll
                for (int m = 0; m < 2; ++m) {
                    f32x4 t0 = __builtin_amdgcn_mfma_f32_16x16x32_bf16(kf0, qf[m][0], zero4(), 0, 0, 0);
                    st[m][jn] = __builtin_amdgcn_mfma_f32_16x16x32_bf16(kf1, qf[m][1], t0, 0, 0, 0);
                }
            }
            __builtin_amdgcn_s_setprio(0);
            if (kb * 64 + 63 > wq0) {           // partial (diagonal) tile: mask
#pragma unroll
                for (int m = 0; m < 2; ++m) {
                    int query = wq0 + m * 16 + c;
#pragma unroll
                    for (int jn = 0; jn < 4; ++jn)
#pragma unroll
                        for (int r = 0; r < 4; ++r)
                            if (kb * 64 + jn * 16 + q * 4 + r > query) st[m][jn][r] = -1e30f;
                }
            }
            // ---- p = exp2(s'); per-lane l partials; pack f16 B-frags
            half4 pa[2][4];
#pragma unroll
            for (int m = 0; m < 2; ++m)
#pragma unroll
                for (int jn = 0; jn < 4; ++jn) {
                    float p0 = exp2f(st[m][jn][0]), p1 = exp2f(st[m][jn][1]);
                    float p2 = exp2f(st[m][jn][2]), p3 = exp2f(st[m][jn][3]);
                    lpart[m] += (p0 + p1) + (p2 + p3);
                    pa[m][jn] = pk4(p0, p1, p2, p3);
                }
            // ---- O^T += V^T P^T  (fused x32: one MFMA per (jnp,dj,m))
            __builtin_amdgcn_s_setprio(1);
#pragma unroll
            for (int jnp = 0; jnp < 2; ++jnp)
#pragma unroll
                for (int dj = 0; dj < 4; ++dj) {
                    half8 vv8 = __builtin_bit_cast(half8,
                        *(const short8*)(Vb + (dj*2 + jnp)*512 + lane*8));
#pragma unroll
                    for (int m = 0; m < 2; ++m) {
                        half4x2 pb;
                        pb.lo = pa[m][2*jnp];
                        pb.hi = pa[m][2*jnp+1];
                        ot[m][dj] = __builtin_amdgcn_mfma_f32_16x16x32_f16(
                            vv8, __builtin_bit_cast(half8, pb), ot[m][dj], 0, 0, 0);
                    }
                }
            __builtin_amdgcn_s_setprio(0);
        }

        // next tile landed + all waves done reading buf[cur^1] (writes target it next iter)
        asm volatile("s_waitcnt vmcnt(0)" ::: "memory");
        __syncthreads();
    }

    // ---- epilogue: quad-reduce l (keys on lanes c,c+16,c+32,c+48), normalize, store
#pragma unroll
    for (int m = 0; m < 2; ++m) {
        float l = lpart[m];
        l += __shfl_xor(l, 16);
        l += __shfl_xor(l, 32);
        float inv = 1.f / l;
        int t = wq0 + m * 16 + c;
        ushort_t* base = AO + ((size_t)b * 2048 + t) * 1024 + hh * 64;
#pragma unroll
        for (int dj = 0; dj < 4; ++dj) {
            ushort4 o;
            o.x = f2bf(ot[m][dj][0] * inv);
            o.y = f2bf(ot[m][dj][1] * inv);
            o.z = f2bf(ot[m][dj][2] * inv);
            o.w = f2bf(ot[m][dj][3] * inv);
            *(ushort4*)(base + dj * 16 + q * 4) = o;
        }
    }
}

extern "C" void kernel_launch(void* const* d_in, const int* in_sizes, int n_in,
                              void* d_out, int out_size, void* d_ws, size_t ws_size,
                              hipStream_t stream) {
    const float* x  = (const float*)d_in[0];
    const float* Wq = (const float*)d_in[2];
    const float* Wk = (const float*)d_in[3];
    const float* Wv = (const float*)d_in[4];
    const float* Wo = (const float*)d_in[5];
    float* out = (float*)d_out;

    ushort_t* ws  = (ushort_t*)d_ws;
    ushort_t* Xb  = ws;                 // 8192x1024 bf16; reused as AO after projections
    ushort_t* Qb  = ws + 8388608;
    ushort_t* Ktb = ws + 16777216;      // bf16, MFMA-fragment-tiled (bh,kb,p,lane,8)
    ushort_t* Vtb = ws + 25165824;      // f16,  MFMA-fragment-tiled (bh,kb,p,lane,8)
    ushort_t* Wqb = ws + 33554432;
    ushort_t* Wkb = Wqb + 1048576;
    ushort_t* Wvb = Wkb + 1048576;
    ushort_t* Wob = Wvb + 1048576;
    float2*   tab = (float2*)(ws + 37748736);   // 512 KB rope table

    cvt_all<<<12544, 256, 0, stream>>>(x, Wq, Wk, Wv, Wo, Xb, Wqb, Wkb, Wvb, Wob, tab);

    // fused QKV: one logical N=3072 GEMM; 128x128 BK=32 dbuf core (unrolled x2)
    gemm_qkv_kernel<<<1536, 256, 0, stream>>>(Xb, Wqb, Wkb, Wvb, tab, Qb, Ktb, Vtb);

    flash_kernel<<<dim3(64, 16), 256, 0, stream>>>(Qb, Ktb, Vtb, Xb);

    gemm_out_kernel<<<256, 512, 0, stream>>>(Xb, Wob, out);
}

// Round 10
// 271.500 us; speedup vs baseline: 1.0852x; 1.0810x over previous
//
#include <hip/hip_runtime.h>
#include <cstdint>
#include <cstddef>

typedef unsigned short ushort_t;
typedef __attribute__((ext_vector_type(8))) short short8;
typedef __attribute__((ext_vector_type(4))) float f32x4;
typedef __attribute__((ext_vector_type(4))) _Float16 half4;
typedef __attribute__((ext_vector_type(8))) _Float16 half8;
typedef __attribute__((ext_vector_type(2))) _Float16 half2;
typedef __attribute__((ext_vector_type(2))) __fp16 fp16v2;
struct half4x2 { half4 lo, hi; };
struct half2x2 { half2 lo, hi; };

__device__ __forceinline__ unsigned short f2bf(float f) {
    unsigned u = __float_as_uint(f);
    u += 0x7fffu + ((u >> 16) & 1u);
    return (unsigned short)(u >> 16);
}
__device__ __forceinline__ float bf2f(unsigned short h) {
    return __uint_as_float((unsigned)h << 16);
}
__device__ __forceinline__ ushort_t f2h(float f) {
    _Float16 h = (_Float16)f;
    return __builtin_bit_cast(unsigned short, h);
}
__device__ __forceinline__ f32x4 zero4() {
    f32x4 z; z[0]=0.f; z[1]=0.f; z[2]=0.f; z[3]=0.f; return z;
}
__device__ __forceinline__ half4 pk4(float a, float b, float cc, float d) {
    half2x2 t;
    t.lo = __builtin_bit_cast(half2, (fp16v2)__builtin_amdgcn_cvt_pkrtz(a, b));
    t.hi = __builtin_bit_cast(half2, (fp16v2)__builtin_amdgcn_cvt_pkrtz(cc, d));
    return __builtin_bit_cast(half4, t);
}
__device__ __forceinline__ void gld_lds16(const ushort_t* g, ushort_t* l) {
    __builtin_amdgcn_global_load_lds(
        (const __attribute__((address_space(1))) void*)g,
        (__attribute__((address_space(3))) void*)l, 16, 0, 0);
}

// ---------------- fused fp32->bf16 convert (x + 4 weights) + rope table, one launch ----------------
__global__ void cvt_all(const float* __restrict__ x,
                        const float* __restrict__ wq, const float* __restrict__ wk,
                        const float* __restrict__ wv, const float* __restrict__ wo,
                        ushort_t* __restrict__ xb,
                        ushort_t* __restrict__ wqb, ushort_t* __restrict__ wkb,
                        ushort_t* __restrict__ wvb, ushort_t* __restrict__ wob,
                        float2* __restrict__ tab) {
    int idx = blockIdx.x * 256 + threadIdx.x;   // grid 12544 blocks exactly
    if (idx >= 3145728) {                        // rope table: 65536 entries
        int i = idx - 3145728;
        int t = i >> 5, p = i & 31;
        float freq = __expf((float)p * -0.2878231366242557f);  // 10000^(-p/32)
        float sn, cs;
        sincosf((float)t * freq, &sn, &cs);
        tab[i] = make_float2(cs, sn);
        return;
    }
    const float* src; ushort_t* dst; int off;
    if (idx < 2097152) { src = x; dst = xb; off = idx; }
    else {
        int r = idx - 2097152;
        int w = r >> 18;
        off = r & 262143;
        src = (w == 0) ? wq : (w == 1) ? wk : (w == 2) ? wv : wo;
        dst = (w == 0) ? wqb : (w == 1) ? wkb : (w == 2) ? wvb : wob;
    }
    float4 v = ((const float4*)src)[off];
    ushort_t o[4];
    o[0] = f2bf(v.x); o[1] = f2bf(v.y); o[2] = f2bf(v.z); o[3] = f2bf(v.w);
    *(ushort4*)(dst + 4*(size_t)off) = *(const ushort4*)o;
}

// ---------------- GEMM core A-db32 (R7, measured 104 us — session best for qkv):
// BM=BN=128, BK=32, 4 waves, 2-phase double-buffer (32 KiB LDS -> high
// co-residency, the m114 lever; VGPR 72). stage(t+1) issued BEFORE compute(t),
// ONE __syncthreads per K-step. XOR swizzle: chunk' = q ^ ((row>>1)&3).
// DO NOT unroll (R9: +24 VGPR, occ 28->20, 104->121) or ring-ify (R8: 125).
// C = A(Mx1024) W(Nx1024)^T.
__device__ __forceinline__ void gemm_core_db32(const ushort_t* __restrict__ A,
                                               const ushort_t* __restrict__ W,
                                               ushort_t* As, ushort_t* Bs,  // each 2*4096 ushorts
                                               int m0, int n0, f32x4 (&acc)[4][4]) {
    const int tid  = threadIdx.x;
    const int wave = tid >> 6, lane = tid & 63;
    const int wm = (wave >> 1) * 64, wn = (wave & 1) * 64;
    const int q = lane >> 4, c = lane & 15;
    const int srow = lane >> 2;                      // 0..15: row within 16-row group
    const int gch  = (lane & 3) ^ ((lane >> 3) & 3); // source chunk (involution w/ read side)

    // staging: wave w covers rows {p*64 + w*16 + srow} for p=0,1 (A and B)
    const ushort_t* ag0 = A + (size_t)(m0 +      wave*16 + srow) * 1024 + gch*8;
    const ushort_t* ag1 = A + (size_t)(m0 + 64 + wave*16 + srow) * 1024 + gch*8;
    const ushort_t* bg0 = W + (size_t)(n0 +      wave*16 + srow) * 1024 + gch*8;
    const ushort_t* bg1 = W + (size_t)(n0 + 64 + wave*16 + srow) * 1024 + gch*8;
    // LDS dest wave-uniform base; HW adds lane*16B: row wave*16+(lane>>2), chunk lane&3
    ushort_t* a0 = As + wave*512;
    ushort_t* a1 = As + 2048 + wave*512;
    ushort_t* b0 = Bs + wave*512;
    ushort_t* b1 = Bs + 2048 + wave*512;

    // prologue: stage K-step 0 into buffer 0
    gld_lds16(ag0, a0); gld_lds16(ag1, a1);
    gld_lds16(bg0, b0); gld_lds16(bg1, b1);
    __syncthreads();                       // drain + publish

    const int ch = (q ^ ((c >> 1) & 3)) * 8;   // read-side swizzled chunk
    int cur = 0;
    for (int t = 0; t < 32; ++t) {
        // ---- issue next K-step's stage FIRST (into the other buffer):
        // latency hides under this step's ds_read+MFMA.
        if (t + 1 < 32) {
            const int nb = cur ^ 1;
            const int kc = (t + 1) * 32;
            gld_lds16(ag0 + kc, a0 + nb*4096);
            gld_lds16(ag1 + kc, a1 + nb*4096);
            gld_lds16(bg0 + kc, b0 + nb*4096);
            gld_lds16(bg1 + kc, b1 + nb*4096);
        }
        // ---- compute current buffer: 8 ds_read_b128, 16 MFMAs
        const ushort_t* Ab = As + cur*4096;
        const ushort_t* Bb = Bs + cur*4096;
        short8 af[4], bf[4];
#pragma unroll
        for (int i = 0; i < 4; ++i)
            af[i] = *(const short8*)(Ab + (wm + i*16 + c)*32 + ch);
#pragma unroll
        for (int j = 0; j < 4; ++j)
            bf[j] = *(const short8*)(Bb + (wn + j*16 + c)*32 + ch);
#pragma unroll
        for (int i = 0; i < 4; ++i)
#pragma unroll
            for (int j = 0; j < 4; ++j)
                acc[i][j] = __builtin_amdgcn_mfma_f32_16x16x32_bf16(af[i], bf[j], acc[i][j], 0, 0, 0);
        // one barrier/step: drains next tile's loads (aged by this compute) and
        // guards buf[cur] against next step's overwrite.
        __syncthreads();
        cur ^= 1;
    }
}

// ---------------- GEMM core B (pipelined; used by the 1-round gemm_out):
// BM=256 BN=128 BK=64, 8 waves, 3-deep LDS ring, counted vmcnt(6).
__device__ __forceinline__ void gemm_pipe256(const ushort_t* __restrict__ A,
                                             const ushort_t* __restrict__ W,
                                             ushort_t* __restrict__ As,   // 3*16384
                                             ushort_t* __restrict__ Bs,   // 3*8192
                                             int m0, int n0, f32x4 (&acc)[4][4]) {
    const int tid  = threadIdx.x;
    const int wave = tid >> 6, lane = tid & 63;
    const int wm = (wave >> 1) * 64, wn = (wave & 1) * 64;
    const int q = lane >> 4, c = lane & 15;
    const int srow = lane >> 3;            // 0..7
    const int gch  = (lane & 7) ^ srow;    // swizzled source chunk

    const ushort_t* ag = A + (size_t)(m0 + wave * 8 + srow) * 1024 + gch * 8;
    const ushort_t* bg = W + (size_t)(n0 + wave * 8 + srow) * 1024 + gch * 8;
    ushort_t* adst = As + wave * 512;
    ushort_t* bdst = Bs + wave * 512;

    // prologue: stage tile0 -> buf0, tile1 -> buf1 (6 loads each, per thread)
#pragma unroll
    for (int n = 0; n < 4; ++n) gld_lds16(ag + (size_t)n * 65536,      adst + n * 4096);
#pragma unroll
    for (int n = 0; n < 2; ++n) gld_lds16(bg + (size_t)n * 65536,      bdst + n * 4096);
#pragma unroll
    for (int n = 0; n < 4; ++n) gld_lds16(ag + (size_t)n * 65536 + 64, adst + 16384 + n * 4096);
#pragma unroll
    for (int n = 0; n < 2; ++n) gld_lds16(bg + (size_t)n * 65536 + 64, bdst + 8192 + n * 4096);
    asm volatile("s_waitcnt vmcnt(6)" ::: "memory");   // tile0 landed; tile1 in flight
    __builtin_amdgcn_s_barrier();

    const int ch0 = (q ^ (c & 7)) * 8;
    const int ch1 = ((4 + q) ^ (c & 7)) * 8;
    int cur = 0;
    for (int t = 0; t < 16; ++t) {
        const int nx2 = (cur >= 1) ? cur - 1 : 2;          // (t+2)%3
        const ushort_t* ab = As + cur * 16384 + (wm + c) * 64;
        const ushort_t* bb = Bs + cur * 8192  + (wn + c) * 64;
        const int kc = (t + 2) * 64;
        const bool pf = (t < 14);
        short8 af[4], bf[4];

        // ---- phase 0: sk=0 frags, stage A0,A1,B0 of tile t+2
#pragma unroll
        for (int i = 0; i < 4; ++i) af[i] = *(const short8*)(ab + i * 1024 + ch0);
#pragma unroll
        for (int j = 0; j < 4; ++j) bf[j] = *(const short8*)(bb + j * 1024 + ch0);
        if (pf) {
            gld_lds16(ag + kc,           adst + nx2 * 16384);
            gld_lds16(ag + 65536 + kc,   adst + nx2 * 16384 + 4096);
            gld_lds16(bg + kc,           bdst + nx2 * 8192);
        }
        __builtin_amdgcn_s_barrier();
        asm volatile("s_waitcnt lgkmcnt(0)" ::: "memory");
        __builtin_amdgcn_s_setprio(1);
#pragma unroll
        for (int i = 0; i < 4; ++i)
#pragma unroll
            for (int j = 0; j < 4; ++j)
                acc[i][j] = __builtin_amdgcn_mfma_f32_16x16x32_bf16(af[i], bf[j], acc[i][j], 0, 0, 0);
        __builtin_amdgcn_s_setprio(0);
        __builtin_amdgcn_s_barrier();

        // ---- phase 1: sk=1 frags, stage A2,A3,B1 of tile t+2
#pragma unroll
        for (int i = 0; i < 4; ++i) af[i] = *(const short8*)(ab + i * 1024 + ch1);
#pragma unroll
        for (int j = 0; j < 4; ++j) bf[j] = *(const short8*)(bb + j * 1024 + ch1);
        if (pf) {
            gld_lds16(ag + 131072 + kc,  adst + nx2 * 16384 + 8192);
            gld_lds16(ag + 196608 + kc,  adst + nx2 * 16384 + 12288);
            gld_lds16(bg + 65536 + kc,   bdst + nx2 * 8192 + 4096);
        }
        __builtin_amdgcn_s_barrier();
        asm volatile("s_waitcnt lgkmcnt(0)" ::: "memory");
        __builtin_amdgcn_s_setprio(1);
#pragma unroll
        for (int i = 0; i < 4; ++i)
#pragma unroll
            for (int j = 0; j < 4; ++j)
                acc[i][j] = __builtin_amdgcn_mfma_f32_16x16x32_bf16(af[i], bf[j], acc[i][j], 0, 0, 0);
        __builtin_amdgcn_s_setprio(0);
        // counted wait: retire tile t+1's 6 loads, leave tile t+2's 6 in flight
        if (pf) { asm volatile("s_waitcnt vmcnt(6)" ::: "memory"); }
        else    { asm volatile("s_waitcnt vmcnt(0)" ::: "memory"); }
        __builtin_amdgcn_s_barrier();
        cur = (cur == 2) ? 0 : cur + 1;
    }
}

// Fused QKV projection as one logical N=3072 GEMM, 1536 blocks (flattened),
// T1 bijective XCD swizzle. RoPE fused via table; K/V written in flash's
// MFMA-fragment-tiled layouts. Core: A-db32 (R7 config — session best).
__global__ __launch_bounds__(256) void gemm_qkv_kernel(
    const ushort_t* __restrict__ X, const ushort_t* __restrict__ Wq,
    const ushort_t* __restrict__ Wk, const ushort_t* __restrict__ Wv,
    const float2* __restrict__ tab,
    ushort_t* __restrict__ Q, ushort_t* __restrict__ Kt, ushort_t* __restrict__ Vt) {
    __shared__ ushort_t As[2 * 4096];
    __shared__ ushort_t Bs[2 * 4096];
    const int orig = blockIdx.x;                 // 0..1535, 1536 % 8 == 0
    const int wg = (orig & 7) * 192 + (orig >> 3);
    const int my = wg / 24;
    const int n24 = wg - my * 24;
    const int which = n24 >> 3;
    const ushort_t* W = (which == 0) ? Wq : (which == 1) ? Wk : Wv;
    const int m0 = my * 128;
    const int nloc0 = (n24 & 7) * 128;           // 0..896 within the selected matrix

    f32x4 acc[4][4];
#pragma unroll
    for (int i = 0; i < 4; ++i)
#pragma unroll
        for (int j = 0; j < 4; ++j) acc[i][j] = zero4();

    gemm_core_db32(X, W, As, Bs, m0, nloc0, acc);

    const int lane = threadIdx.x & 63, wave = threadIdx.x >> 6;
    const int q = lane >> 4, c = lane & 15;
    const int wm = (wave >> 1) * 64, wn = (wave & 1) * 64;
    const float scale = (which == 0) ? 0.18033688011112042f : 1.0f;  // 0.125*log2(e) for Q

#pragma unroll
    for (int i = 0; i < 4; ++i)
#pragma unroll
        for (int j = 0; j < 4; ++j) {
            int nn = nloc0 + wn + j*16 + c;      // col within matrix: h*64+d
            int d = nn & 63, h = nn >> 6;
            int pidx = d >> 1;
            float sgn = (d & 1) ? 1.f : -1.f;
#pragma unroll
            for (int r = 0; r < 4; ++r) {
                int mm = m0 + wm + i*16 + q*4 + r;   // row: b*2048+t
                int b = mm >> 11, t = mm & 2047;
                float val = acc[i][j][r];
                if (which == 0) {      // Q: rope + (B,H,T,64) bf16 row-major
                    float partner = __shfl_xor(val, 1);
                    float2 cs = tab[t * 32 + pidx];
                    val = (val * cs.x + sgn * partner * cs.y) * scale;
                    Q[((size_t)((b << 4) + h) * 2048 + t) * 64 + d] = f2bf(val);
                } else if (which == 1) {  // K: rope + scatter into tiled bf16 layout
                    float partner = __shfl_xor(val, 1);
                    float2 cs = tab[t * 32 + pidx];
                    val = val * cs.x + sgn * partner * cs.y;
                    int kb = t >> 6, jn = (t >> 4) & 3, cc2 = t & 15;
                    int ks2 = d >> 5, qq2 = (d >> 3) & 3, e = d & 7;
                    int lane2 = qq2 * 16 + cc2;
                    Kt[((((size_t)((b << 4) + h) * 32 + kb) * 8 + jn * 2 + ks2) << 9) + lane2 * 8 + e] = f2bf(val);
                } else {               // V: scatter into tiled f16 layout
                    int kb = t >> 6, kl = t & 63;
                    int jn = kl >> 4, qq2 = (kl >> 2) & 3;
                    int e = ((jn & 1) << 2) | (kl & 3);
                    int p = ((d >> 4) << 1) | (jn >> 1);
                    int lane2 = qq2 * 16 + (d & 15);
                    Vt[((((size_t)((b << 4) + h) * 32 + kb) * 8 + p) << 9) + lane2 * 8 + e] = f2h(val);
                }
            }
        }
}

__global__ __launch_bounds__(512) void gemm_out_kernel(
    const ushort_t* __restrict__ A, const ushort_t* __restrict__ Wo,
    float* __restrict__ OUT) {
    __shared__ ushort_t As[3 * 16384];
    __shared__ ushort_t Bs[3 * 8192];
    // 256 blocks (32 m-tiles x 8 n-tiles) = exactly 1/CU, XCD-swizzled
    const int orig = blockIdx.x;
    const int wg = (orig & 7) * 32 + (orig >> 3);
    const int m0 = (wg >> 3) * 256, n0 = (wg & 7) * 128;

    f32x4 acc[4][4];
#pragma unroll
    for (int i = 0; i < 4; ++i)
#pragma unroll
        for (int j = 0; j < 4; ++j) acc[i][j] = zero4();

    gemm_pipe256(A, Wo, As, Bs, m0, n0, acc);

    const int lane = threadIdx.x & 63, wave = threadIdx.x >> 6;
    const int q = lane >> 4, c = lane & 15;
    const int wm = (wave >> 1) * 64, wn = (wave & 1) * 64;
#pragma unroll
    for (int i = 0; i < 4; ++i)
#pragma unroll
        for (int j = 0; j < 4; ++j)
#pragma unroll
            for (int r = 0; r < 4; ++r) {
                int mm = m0 + wm + i*16 + q*4 + r;
                int nn = n0 + wn + j*16 + c;
                OUT[(size_t)mm * 1024 + nn] = acc[i][j][r];
            }
}

// ---------------- Flash attention v9: prefetch double-buffer + PV fused x32 f16
// + T5 setprio around MFMA clusters (m191: +4-7% attn at multi-block/CU).
__global__ __launch_bounds__(256, 3) void flash_kernel(
    const ushort_t* __restrict__ Q, const ushort_t* __restrict__ Kt,
    const ushort_t* __restrict__ Vt, ushort_t* __restrict__ AO) {
    __shared__ ushort_t Ks[2][4096];   // 64x64 bf16 K tiles, fragment-tiled
    __shared__ ushort_t Vs[2][4096];   // 64x64 f16 V tiles, fragment-tiled
    const int bh = blockIdx.x;
    const int c0 = 15 - blockIdx.y;             // LPT: big chunks first
    const int w  = threadIdx.x >> 6, lane = threadIdx.x & 63;
    const int q = lane >> 4, c = lane & 15;
    const int qlo = c0 * 128;
    const int nt  = 2 * c0 + 2;                 // 64-key tiles
    const int wq0 = qlo + w * 32;               // this wave's first query
    const int b = bh >> 4, hh = bh & 15;

    const ushort_t* Qp = Q + (size_t)bh * 131072;
    const ushort_t* kt0 = Kt + (size_t)bh * 131072;
    const ushort_t* vt0 = Vt + (size_t)bh * 131072;

    short8 qf[2][2];
#pragma unroll
    for (int m = 0; m < 2; ++m)
#pragma unroll
        for (int ks = 0; ks < 2; ++ks)
            qf[m][ks] = *(const short8*)(Qp + (size_t)(wq0 + m*16 + c) * 64 + ks * 32 + q * 8);

    f32x4 ot[2][4];
#pragma unroll
    for (int m = 0; m < 2; ++m)
#pragma unroll
        for (int dj = 0; dj < 4; ++dj) ot[m][dj] = zero4();
    float lpart[2] = {0.f, 0.f};

    // prologue: stage tile 0 -> buf 0
#pragma unroll
    for (int s = 0; s < 2; ++s) {
        gld_lds16(kt0 + (s*4 + w)*512 + lane*8, &Ks[0][(s*4 + w)*512]);
        gld_lds16(vt0 + (s*4 + w)*512 + lane*8, &Vs[0][(s*4 + w)*512]);
    }
    asm volatile("s_waitcnt vmcnt(0)" ::: "memory");
    __syncthreads();

    for (int kb = 0; kb < nt; ++kb) {
        const int cur = kb & 1;
        // ---- issue next tile's stage FIRST: latency hides under this tile's compute
        if (kb + 1 < nt) {
            const ushort_t* kt = kt0 + (size_t)(kb + 1) * 4096;
            const ushort_t* vt = vt0 + (size_t)(kb + 1) * 4096;
#pragma unroll
            for (int s = 0; s < 2; ++s) {
                gld_lds16(kt + (s*4 + w)*512 + lane*8, &Ks[cur ^ 1][(s*4 + w)*512]);
                gld_lds16(vt + (s*4 + w)*512 + lane*8, &Vs[cur ^ 1][(s*4 + w)*512]);
            }
        }

        if (kb * 64 <= wq0 + 31) {              // not fully masked for this wave
            const ushort_t* Kb = &Ks[cur][0];
            const ushort_t* Vb = &Vs[cur][0];
            // ---- S^T = K Q^T : row=key(q*4+r), col=query(c)
            f32x4 st[2][4];
            __builtin_amdgcn_s_setprio(1);
#pragma unroll
            for (int jn = 0; jn < 4; ++jn) {
                short8 kf0 = *(const short8*)(Kb + (jn*2+0)*512 + lane*8);
                short8 kf1 = *(const short8*)(Kb + (jn*2+1)*512 + lane*8);
#pragma unroll
                for (int m = 0; m < 2; ++m) {
                    f32x4 t0 = __builtin_amdgcn_mfma_f32_16x16x32_bf16(kf0, qf[m][0], zero4(), 0, 0, 0);
                    st[m][jn] = __builtin_amdgcn_mfma_f32_16x16x32_bf16(kf1, qf[m][1], t0, 0, 0, 0);
                }
            }
            __builtin_amdgcn_s_setprio(0);
            if (kb * 64 + 63 > wq0) {           // partial (diagonal) tile: mask
#pragma unroll
                for (int m = 0; m < 2; ++m) {
                    int query = wq0 + m * 16 + c;
#pragma unroll
                    for (int jn = 0; jn < 4; ++jn)
#pragma unroll
                        for (int r = 0; r < 4; ++r)
                            if (kb * 64 + jn * 16 + q * 4 + r > query) st[m][jn][r] = -1e30f;
                }
            }
            // ---- p = exp2(s'); per-lane l partials; pack f16 B-frags
            half4 pa[2][4];
#pragma unroll
            for (int m = 0; m < 2; ++m)
#pragma unroll
                for (int jn = 0; jn < 4; ++jn) {
                    float p0 = exp2f(st[m][jn][0]), p1 = exp2f(st[m][jn][1]);
                    float p2 = exp2f(st[m][jn][2]), p3 = exp2f(st[m][jn][3]);
                    lpart[m] += (p0 + p1) + (p2 + p3);
                    pa[m][jn] = pk4(p0, p1, p2, p3);
                }
            // ---- O^T += V^T P^T  (fused x32: one MFMA per (jnp,dj,m))
            __builtin_amdgcn_s_setprio(1);
#pragma unroll
            for (int jnp = 0; jnp < 2; ++jnp)
#pragma unroll
                for (int dj = 0; dj < 4; ++dj) {
                    half8 vv8 = __builtin_bit_cast(half8,
                        *(const short8*)(Vb + (dj*2 + jnp)*512 + lane*8));
#pragma unroll
                    for (int m = 0; m < 2; ++m) {
                        half4x2 pb;
                        pb.lo = pa[m][2*jnp];
                        pb.hi = pa[m][2*jnp+1];
                        ot[m][dj] = __builtin_amdgcn_mfma_f32_16x16x32_f16(
                            vv8, __builtin_bit_cast(half8, pb), ot[m][dj], 0, 0, 0);
                    }
                }
            __builtin_amdgcn_s_setprio(0);
        }

        // next tile landed + all waves done reading buf[cur^1] (writes target it next iter)
        asm volatile("s_waitcnt vmcnt(0)" ::: "memory");
        __syncthreads();
    }

    // ---- epilogue: quad-reduce l (keys on lanes c,c+16,c+32,c+48), normalize, store
#pragma unroll
    for (int m = 0; m < 2; ++m) {
        float l = lpart[m];
        l += __shfl_xor(l, 16);
        l += __shfl_xor(l, 32);
        float inv = 1.f / l;
        int t = wq0 + m * 16 + c;
        ushort_t* base = AO + ((size_t)b * 2048 + t) * 1024 + hh * 64;
#pragma unroll
        for (int dj = 0; dj < 4; ++dj) {
            ushort4 o;
            o.x = f2bf(ot[m][dj][0] * inv);
            o.y = f2bf(ot[m][dj][1] * inv);
            o.z = f2bf(ot[m][dj][2] * inv);
            o.w = f2bf(ot[m][dj][3] * inv);
            *(ushort4*)(base + dj * 16 + q * 4) = o;
        }
    }
}

extern "C" void kernel_launch(void* const* d_in, const int* in_sizes, int n_in,
                              void* d_out, int out_size, void* d_ws, size_t ws_size,
                              hipStream_t stream) {
    const float* x  = (const float*)d_in[0];
    const float* Wq = (const float*)d_in[2];
    const float* Wk = (const float*)d_in[3];
    const float* Wv = (const float*)d_in[4];
    const float* Wo = (const float*)d_in[5];
    float* out = (float*)d_out;

    ushort_t* ws  = (ushort_t*)d_ws;
    ushort_t* Xb  = ws;                 // 8192x1024 bf16; reused as AO after projections
    ushort_t* Qb  = ws + 8388608;
    ushort_t* Ktb = ws + 16777216;      // bf16, MFMA-fragment-tiled (bh,kb,p,lane,8)
    ushort_t* Vtb = ws + 25165824;      // f16,  MFMA-fragment-tiled (bh,kb,p,lane,8)
    ushort_t* Wqb = ws + 33554432;
    ushort_t* Wkb = Wqb + 1048576;
    ushort_t* Wvb = Wkb + 1048576;
    ushort_t* Wob = Wvb + 1048576;
    float2*   tab = (float2*)(ws + 37748736);   // 512 KB rope table

    cvt_all<<<12544, 256, 0, stream>>>(x, Wq, Wk, Wv, Wo, Xb, Wqb, Wkb, Wvb, Wob, tab);

    // fused QKV: one logical N=3072 GEMM; 128x128 BK=32 dbuf core (R7 config)
    gemm_qkv_kernel<<<1536, 256, 0, stream>>>(Xb, Wqb, Wkb, Wvb, tab, Qb, Ktb, Vtb);

    flash_kernel<<<dim3(64, 16), 256, 0, stream>>>(Qb, Ktb, Vtb, Xb);

    gemm_out_kernel<<<256, 512, 0, stream>>>(Xb, Wob, out);
}